// Round 1
// baseline (577.570 us; speedup 1.0000x reference)
//
#include <hip/hip_runtime.h>

// Shapes (fixed by the problem):
//   B=16, T_his=4095, T=4096, hid=2048, H=16, dh=128
// d_out layout (f32): K_out [16][4096][2048] | V_out [16][4096][2048] | v_next [16][2048]
// K_out[b][h*256 + t/16][(t%16)*128 + d] = K[b][t][h*128+d], K = concat(K_his, k_new)
// v_next = (sum_t V[b,t,:]) @ W_proj + b_proj   (softmax over size-1 axis == ones; q is dead)

__global__ void init_kernel(const float* __restrict__ b_attn,
                            const float* __restrict__ b_proj,
                            float* __restrict__ qkv,      // [16][4096] (k | v)
                            float* __restrict__ colsum,   // [16][2048]
                            float* __restrict__ vnext) {  // [16][2048] in d_out
  int tid = blockIdx.x * blockDim.x + threadIdx.x;   // 65536 threads
  qkv[tid] = b_attn[2048 + (tid & 4095)];            // bias for k,v columns
  if (tid < 32768) {
    colsum[tid] = 0.0f;
    vnext[tid] = b_proj[tid & 2047];
  }
}

// Partial GEMM: out[b][col0'..] += X[16][2048] @ W[2048][ldw] (columns col0..col0+ncols)
// grid.x = ncols/512 (256 thr * 2 cols), grid.y = 2048/64 k-chunks. Atomic accumulate.
__global__ void small_gemm_atomic(const float* __restrict__ X,
                                  const float* __restrict__ W,
                                  int ldw, int col0,
                                  float* __restrict__ out, int ncols) {
  int j  = blockIdx.x * 512 + threadIdx.x * 2;
  int k0 = blockIdx.y * 64;
  const float* wp = W + (size_t)k0 * ldw + col0 + j;
  float2 acc[16];
#pragma unroll
  for (int b = 0; b < 16; ++b) acc[b] = make_float2(0.f, 0.f);
  for (int kk = 0; kk < 64; ++kk) {
    float2 w = *(const float2*)(wp + (size_t)kk * ldw);
    const float* xp = X + k0 + kk;
#pragma unroll
    for (int b = 0; b < 16; ++b) {
      float xv = xp[(size_t)b * 2048];   // wave-uniform -> scalar load, L1/L2 hit
      acc[b].x = fmaf(xv, w.x, acc[b].x);
      acc[b].y = fmaf(xv, w.y, acc[b].y);
    }
  }
#pragma unroll
  for (int b = 0; b < 16; ++b) {
    atomicAdd(&out[b * ncols + j],     acc[b].x);
    atomicAdd(&out[b * ncols + j + 1], acc[b].y);
  }
}

// The big fused kernel: head-major transposed copy of K and V into d_out,
// with V column-sums accumulated into colsum.
// grid = (4096 output rows, 16 batches, 2 {K,V}), block = 256.
__global__ void copy_transpose(const float* __restrict__ K_his,
                               const float* __restrict__ V_his,
                               const float* __restrict__ qkv,   // [16][4096] (k|v)
                               float* __restrict__ out,
                               float* __restrict__ colsum) {
  const int i     = blockIdx.x;       // output row within batch
  const int b     = blockIdx.y;
  const int which = blockIdx.z;       // 0=K, 1=V
  const int h     = i >> 8;
  const int tbase = (i & 255) << 4;
  const int tid   = threadIdx.x;

  const float* src  = which ? V_his : K_his;
  const float* qsrc = qkv + b * 4096 + which * 2048;
  float* orow = out + (size_t)which * 134217728ull + (size_t)b * 8388608ull
                    + (size_t)i * 2048u;

  __shared__ float4 red[128];

  float4 acc = make_float4(0.f, 0.f, 0.f, 0.f);
#pragma unroll
  for (int iter = 0; iter < 2; ++iter) {
    int j = iter * 1024 + tid * 4;
    int s = j >> 7;            // t sub-index within row (0..15)
    int d = j & 127;           // channel within head
    int t = tbase + s;
    float4 val;
    if (t < 4095)
      val = *(const float4*)(src + (size_t)b * 8386560ull + (size_t)t * 2048u
                                 + (unsigned)(h * 128 + d));
    else
      val = *(const float4*)(qsrc + h * 128 + d);   // appended k/v row from qkv
    *(float4*)(orow + j) = val;
    acc.x += val.x; acc.y += val.y; acc.z += val.z; acc.w += val.w;
  }

  if (which) {
    // Each thread's d-range is fixed: d = (tid&31)*4. Reduce over the 16 t's
    // this block covers: lanes l and l+32 share d -> shfl_xor(32); then across
    // the 4 waves via LDS; 128 atomics/block into colsum.
    acc.x += __shfl_xor(acc.x, 32);
    acc.y += __shfl_xor(acc.y, 32);
    acc.z += __shfl_xor(acc.z, 32);
    acc.w += __shfl_xor(acc.w, 32);
    int lane = tid & 63;
    int wave = tid >> 6;
    if (lane < 32) red[wave * 32 + lane] = acc;
    __syncthreads();
    if (tid < 32) {
      float4 a0 = red[tid], a1 = red[32 + tid], a2 = red[64 + tid], a3 = red[96 + tid];
      float* cp = colsum + b * 2048 + h * 128 + tid * 4;
      atomicAdd(cp + 0, a0.x + a1.x + a2.x + a3.x);
      atomicAdd(cp + 1, a0.y + a1.y + a2.y + a3.y);
      atomicAdd(cp + 2, a0.z + a1.z + a2.z + a3.z);
      atomicAdd(cp + 3, a0.w + a1.w + a2.w + a3.w);
    }
  }
}

extern "C" void kernel_launch(void* const* d_in, const int* in_sizes, int n_in,
                              void* d_out, int out_size, void* d_ws, size_t ws_size,
                              hipStream_t stream) {
  const float* x      = (const float*)d_in[0];
  const float* K_his  = (const float*)d_in[1];
  const float* V_his  = (const float*)d_in[2];
  const float* W_attn = (const float*)d_in[3];
  const float* b_attn = (const float*)d_in[4];
  const float* W_proj = (const float*)d_in[5];
  const float* b_proj = (const float*)d_in[6];
  // d_in[7] = n_head (16), hard-coded.

  float* out    = (float*)d_out;
  float* qkv    = (float*)d_ws;            // 16*4096 f32 = 256 KB
  float* colsum = qkv + 16 * 4096;         // 16*2048 f32 = 128 KB
  float* vnext  = out + 268435456ull;      // third output region

  // A: init qkv=bias(k,v), colsum=0, vnext=b_proj
  init_kernel<<<256, 256, 0, stream>>>(b_attn, b_proj, qkv, colsum, vnext);

  // B: qkv += x @ W_attn[:, 2048:6144]   (skip dead q columns)
  small_gemm_atomic<<<dim3(8, 32), 256, 0, stream>>>(x, W_attn, 6144, 2048, qkv, 4096);

  // C: transposed copy of K and V (+ appended row) + V column sums
  copy_transpose<<<dim3(4096, 16, 2), 256, 0, stream>>>(K_his, V_his, qkv, out, colsum);

  // D: vnext += colsum @ W_proj
  small_gemm_atomic<<<dim3(4, 32), 256, 0, stream>>>(colsum, W_proj, 2048, 0, vnext, 2048);
}

// Round 3
// 465.511 us; speedup vs baseline: 1.2407x; 1.2407x over previous
//
#include <hip/hip_runtime.h>

// Shapes (fixed): B=16, T_his=4095, T=4096, hid=2048, H=16, dh=128
// d_out layout (f32): K_out [16][4096][2048] | V_out [16][4096][2048] | v_next [16][2048]
// K_out[b][h*256 + t/16][(t%16)*128 + d] = K[b][t][h*128+d], K = concat(K_his, k_new)
// v_next = (sum_t V[b,t,:]) @ W_proj + b_proj   (softmax over size-1 axis == ones; q dead)

typedef float f4 __attribute__((ext_vector_type(4)));   // native vector: OK for nontemporal builtins

__global__ void init_kernel(const float* __restrict__ b_attn,
                            const float* __restrict__ b_proj,
                            float* __restrict__ qkv,      // [16][4096] (k | v)
                            float* __restrict__ colsum,   // [16][2048]
                            float* __restrict__ vnext) {  // [16][2048] in d_out
  int tid = blockIdx.x * blockDim.x + threadIdx.x;   // 65536 threads
  qkv[tid] = b_attn[2048 + (tid & 4095)];            // bias for k,v columns
  if (tid < 32768) {
    colsum[tid] = 0.0f;
    vnext[tid] = b_proj[tid & 2047];
  }
}

// Partial GEMM: out[b][j] += X[16][2048] @ W[2048][ldw] (cols col0..col0+ncols)
__global__ void small_gemm_atomic(const float* __restrict__ X,
                                  const float* __restrict__ W,
                                  int ldw, int col0,
                                  float* __restrict__ out, int ncols) {
  int j  = blockIdx.x * 512 + threadIdx.x * 2;
  int k0 = blockIdx.y * 64;
  const float* wp = W + (size_t)k0 * ldw + col0 + j;
  float2 acc[16];
#pragma unroll
  for (int b = 0; b < 16; ++b) acc[b] = make_float2(0.f, 0.f);
  for (int kk = 0; kk < 64; ++kk) {
    float2 w = *(const float2*)(wp + (size_t)kk * ldw);
    const float* xp = X + k0 + kk;
#pragma unroll
    for (int b = 0; b < 16; ++b) {
      float xv = xp[(size_t)b * 2048];
      acc[b].x = fmaf(xv, w.x, acc[b].x);
      acc[b].y = fmaf(xv, w.y, acc[b].y);
    }
  }
#pragma unroll
  for (int b = 0; b < 16; ++b) {
    atomicAdd(&out[b * ncols + j],     acc[b].x);
    atomicAdd(&out[b * ncols + j + 1], acc[b].y);
  }
}

// Head-major transposed streaming copy of K and V + fused V column-sum.
// grid = (512 row-groups of 8, 16 batches, 2 {K,V}), block = 256.
// Per block: 8 output rows = 64 KB read + 64 KB write, one reduction epilogue.
__global__ void __launch_bounds__(256)
copy_transpose(const float* __restrict__ K_his,
               const float* __restrict__ V_his,
               const float* __restrict__ qkv,   // [16][4096] (k|v)
               float* __restrict__ out,
               float* __restrict__ colsum) {
  const int b     = blockIdx.y;
  const int which = blockIdx.z;                 // 0=K, 1=V
  const int i0    = blockIdx.x * 8;             // first of 8 output rows
  const int h     = i0 >> 8;                    // head (constant across the 8 rows)
  const int tid   = threadIdx.x;
  const int d     = (tid * 4) & 127;            // channel offset, fixed per thread
  const int s0    = tid >> 5;                   // t sub-index 0..7 (and s0+8)
  const int tb0   = (i0 & 255) * 16;

  const float* src  = which ? V_his : K_his;
  const float* qrow = qkv + b * 4096 + which * 2048 + h * 128 + d;   // appended row
  const float* base = src + (size_t)b * 8386560ull + (unsigned)(h * 128 + d);
  float* orow = out + ((size_t)which << 27) + ((size_t)b << 23)
                    + (size_t)i0 * 2048u + (unsigned)(tid * 4);

  __shared__ f4 red[128];

  f4 acc = {0.f, 0.f, 0.f, 0.f};
#pragma unroll
  for (int r = 0; r < 8; ++r) {
    const int trow = tb0 + r * 16;
    const int t0 = trow + s0;
    const int t1 = trow + s0 + 8;
    const float* p0 = (t0 == 4095) ? qrow : base + (size_t)t0 * 2048u;
    const float* p1 = (t1 == 4095) ? qrow : base + (size_t)t1 * 2048u;
    f4 v0 = __builtin_nontemporal_load((const f4*)p0);
    f4 v1 = __builtin_nontemporal_load((const f4*)p1);
    __builtin_nontemporal_store(v0, (f4*)(orow + r * 2048));
    __builtin_nontemporal_store(v1, (f4*)(orow + r * 2048 + 1024));
    acc += v0 + v1;
  }

  if (which) {
    // lanes l and l+32 share d -> combine, then across the 4 waves via LDS.
    acc.x += __shfl_xor(acc.x, 32);
    acc.y += __shfl_xor(acc.y, 32);
    acc.z += __shfl_xor(acc.z, 32);
    acc.w += __shfl_xor(acc.w, 32);
    int lane = tid & 63;
    int wave = tid >> 6;
    if (lane < 32) red[wave * 32 + lane] = acc;
    __syncthreads();
    if (tid < 32) {
      f4 a = red[tid] + red[32 + tid] + red[64 + tid] + red[96 + tid];
      float* cp = colsum + b * 2048 + h * 128 + tid * 4;
      atomicAdd(cp + 0, a.x);
      atomicAdd(cp + 1, a.y);
      atomicAdd(cp + 2, a.z);
      atomicAdd(cp + 3, a.w);
    }
  }
}

extern "C" void kernel_launch(void* const* d_in, const int* in_sizes, int n_in,
                              void* d_out, int out_size, void* d_ws, size_t ws_size,
                              hipStream_t stream) {
  const float* x      = (const float*)d_in[0];
  const float* K_his  = (const float*)d_in[1];
  const float* V_his  = (const float*)d_in[2];
  const float* W_attn = (const float*)d_in[3];
  const float* b_attn = (const float*)d_in[4];
  const float* W_proj = (const float*)d_in[5];
  const float* b_proj = (const float*)d_in[6];

  float* out    = (float*)d_out;
  float* qkv    = (float*)d_ws;            // 16*4096 f32 = 256 KB
  float* colsum = qkv + 16 * 4096;         // 16*2048 f32 = 128 KB
  float* vnext  = out + 268435456ull;      // third output region

  init_kernel<<<256, 256, 0, stream>>>(b_attn, b_proj, qkv, colsum, vnext);
  small_gemm_atomic<<<dim3(8, 32), 256, 0, stream>>>(x, W_attn, 6144, 2048, qkv, 4096);
  copy_transpose<<<dim3(512, 16, 2), 256, 0, stream>>>(K_his, V_his, qkv, out, colsum);
  small_gemm_atomic<<<dim3(4, 32), 256, 0, stream>>>(colsum, W_proj, 2048, 0, vnext, 2048);
}